// Round 10
// baseline (57.927 us; speedup 1.0000x reference)
//
#include <hip/hip_runtime.h>
#include <math.h>

#define B_DIM   64
#define T_DIM   1024
#define E_DIM   512
#define DL_DIM  1024
#define DA_DIM  128
#define CL_DIM  32
#define KW      31
#define KWP     32   // padded conv width (k=31 is zero)

typedef float vf4 __attribute__((ext_vector_type(4)));
typedef float vf2 __attribute__((ext_vector_type(2)));

// ws layout (float offsets)
#define WS_WCOMB 0            // 128*32 = 4096 (stride-32 padded rows)
#define WS_BCOMB 4096         // 128
#define WS_PL    4224         // 64*128 = 8192
#define WS_EN    16384        // 64*1024 = 65536
// total 81920 floats = 328 KB

// ---------------------------------------------------------------------------
// K1: blocks 0..255: processed_lstm. Block (b,q): rows a in [q*32, q*32+32).
//     8 threads per row, each a 128-elem sub-dot, 3-step shfl reduce.
//     block 256: Wcomb (stride-32, k=31 zeroed) and bcomb.
// ---------------------------------------------------------------------------
__global__ __launch_bounds__(256) void prep_kernel(
    const float* __restrict__ lstm,    // [B,1,DL]
    const float* __restrict__ W_lstm,  // [DA,DL]
    const float* __restrict__ conv_w,  // [CL,1,KW]
    const float* __restrict__ conv_b,  // [CL]
    const float* __restrict__ W_loc,   // [DA,CL]
    const float* __restrict__ b_loc,   // [DA]
    float* __restrict__ ws) {
  const int blk = blockIdx.x;
  const int tid = threadIdx.x;
  if (blk < 4 * B_DIM) {
    const int b = blk >> 2;
    const int q = blk & 3;
    const int a = q * 32 + (tid >> 3);  // 32 rows per block
    const int h = tid & 7;              // 8 sub-dots per row
    const float4* lv = (const float4*)(lstm + (size_t)b * DL_DIM + h * 128);
    const float4* wv = (const float4*)(W_lstm + (size_t)a * DL_DIM + h * 128);
    float acc = 0.f;
#pragma unroll 8
    for (int i = 0; i < 32; ++i) {
      const float4 x = lv[i], y = wv[i];
      acc = fmaf(x.x, y.x, acc);
      acc = fmaf(x.y, y.y, acc);
      acc = fmaf(x.z, y.z, acc);
      acc = fmaf(x.w, y.w, acc);
    }
    acc += __shfl_xor(acc, 1);
    acc += __shfl_xor(acc, 2);
    acc += __shfl_xor(acc, 4);
    if (h == 0) ws[WS_PL + b * DA_DIM + a] = acc;
  } else if (tid < DA_DIM) {
    const int a = tid;
    float wl[CL_DIM];
#pragma unroll
    for (int c = 0; c < CL_DIM; ++c) wl[c] = W_loc[a * CL_DIM + c];
    float bc = b_loc[a];
#pragma unroll
    for (int c = 0; c < CL_DIM; ++c) bc = fmaf(wl[c], conv_b[c], bc);
    ws[WS_BCOMB + a] = bc;
    for (int k = 0; k < KWP; ++k) {
      float s = 0.f;
      if (k < KW) {
#pragma unroll
        for (int c = 0; c < CL_DIM; ++c) s = fmaf(wl[c], conv_w[c * KW + k], s);
      }
      ws[WS_WCOMB + a * KWP + k] = s;
    }
  }
}

// ---------------------------------------------------------------------------
// K2: energies. grid (16,64), block 256 = 4 waves; wave w owns 16 t's.
// All FMA operands register-resident; peo read via NON-TEMPORAL loads
// (stream-once, no L2 allocate); one LDS transpose reduce at the end.
// ---------------------------------------------------------------------------
#define TCHUNK 64
__global__ __launch_bounds__(256, 2) void energy_kernel(
    const float* __restrict__ peo,  // [B,T,DA]
    const float* __restrict__ awc,  // [B,T]
    const float* __restrict__ W_e,  // [DA]
    const float* __restrict__ b_e,  // [1]
    float* __restrict__ ws) {
  const int b = blockIdx.y;
  const int t0 = blockIdx.x * TCHUNK;
  const int tid = threadIdx.x;
  const int lane = tid & 63;
  const int wave = tid >> 6;

  __shared__ float s_awc[96];          // window [t0-15, t0+80], pad zeros
  __shared__ float s_red[4][16][68];   // per-wave transpose buffer (pad 68)

  for (int i = tid; i < 96; i += 256) {
    const int g = t0 - (KW / 2) + i;
    s_awc[i] = (i < TCHUNK + KW - 1 && g >= 0 && g < T_DIM) ? awc[b * T_DIM + g] : 0.f;
  }
  __syncthreads();

  // ---- register copies: awc window (48) and Wcomb rows (2x32) ----
  float aw[48];
  {
    const float4* awp = (const float4*)(s_awc + wave * 16);
#pragma unroll
    for (int j = 0; j < 12; ++j) {
      const float4 q = awp[j];
      aw[4 * j + 0] = q.x; aw[4 * j + 1] = q.y;
      aw[4 * j + 2] = q.z; aw[4 * j + 3] = q.w;
    }
  }
  const int a0 = 2 * lane, a1 = 2 * lane + 1;
  float wc0[KWP], wc1[KWP];
  {
    const float4* w0p = (const float4*)(ws + WS_WCOMB + a0 * KWP);
    const float4* w1p = (const float4*)(ws + WS_WCOMB + a1 * KWP);
#pragma unroll
    for (int j = 0; j < 8; ++j) {
      const float4 q0 = w0p[j], q1 = w1p[j];
      wc0[4 * j + 0] = q0.x; wc0[4 * j + 1] = q0.y;
      wc0[4 * j + 2] = q0.z; wc0[4 * j + 3] = q0.w;
      wc1[4 * j + 0] = q1.x; wc1[4 * j + 1] = q1.y;
      wc1[4 * j + 2] = q1.z; wc1[4 * j + 3] = q1.w;
    }
  }
  const float base0 = ws[WS_PL + b * DA_DIM + a0] + ws[WS_BCOMB + a0];
  const float base1 = ws[WS_PL + b * DA_DIM + a1] + ws[WS_BCOMB + a1];
  const float we0 = W_e[a0], we1 = W_e[a1];
  const float be = b_e[0];

  // ---- main loop: 16 t's, all operands in registers ----
  float v[16];
#pragma unroll
  for (int i = 0; i < 16; ++i) {
    const int t = t0 + wave * 16 + i;
    const vf2 p = __builtin_nontemporal_load(
        (const vf2*)(peo + ((size_t)b * T_DIM + t) * DA_DIM + a0));
    float s0 = base0, s1 = base1;
#pragma unroll
    for (int k = 0; k < KWP; ++k) {
      s0 = fmaf(aw[i + k], wc0[k], s0);
      s1 = fmaf(aw[i + k], wc1[k], s1);
    }
    const float x0 = s0 + p.x;
    const float x1 = s1 + p.y;
    // overflow-safe tanh: sign(x)*(1-e)*rcp(1+e), e = exp(-2|x|)
    const float e0 = __expf(-2.f * fabsf(x0));
    const float e1 = __expf(-2.f * fabsf(x1));
    const float th0 = __builtin_copysignf((1.f - e0) * __builtin_amdgcn_rcpf(1.f + e0), x0);
    const float th1 = __builtin_copysignf((1.f - e1) * __builtin_amdgcn_rcpf(1.f + e1), x1);
    v[i] = fmaf(th0, we0, th1 * we1);
  }

  // ---- transpose reduce: 64 partials per t -> 1 energy, 16 t's at once ----
#pragma unroll
  for (int i = 0; i < 16; ++i) s_red[wave][i][lane] = v[i];
  __syncthreads();
  {
    const int t = lane >> 2;   // 0..15
    const int sub = lane & 3;  // 0..3
    const float4* rp = (const float4*)(&s_red[wave][t][sub * 16]);
    float4 q0 = rp[0], q1 = rp[1], q2 = rp[2], q3 = rp[3];
    float s = ((q0.x + q0.y) + (q0.z + q0.w)) + ((q1.x + q1.y) + (q1.z + q1.w))
            + ((q2.x + q2.y) + (q2.z + q2.w)) + ((q3.x + q3.y) + (q3.z + q3.w));
    s += __shfl_xor(s, 1);
    s += __shfl_xor(s, 2);
    if (sub == 0)
      ws[WS_EN + b * T_DIM + t0 + wave * 16 + t] = s + be;
  }
}

// ---------------------------------------------------------------------------
// K3: fused softmax + context over a 32-column chunk x ALL 1024 t (R8 shape),
// enc read via NON-TEMPORAL loads (stream-once, no L2 allocate).
// grid (16,64), block 256. Disjoint columns -> no cross-block communication.
// ---------------------------------------------------------------------------
__global__ __launch_bounds__(256) void context_kernel(
    const float* __restrict__ enc,  // [B,T,E]
    const float* __restrict__ ws,
    float* __restrict__ out) {      // [B*E context][B*T weights]
  const int b = blockIdx.y;
  const int ec = blockIdx.x;  // 0..15 (columns ec*32 .. ec*32+32)
  const int tid = threadIdx.x;
  const int lane = tid & 63;
  const int wave = tid >> 6;

  __shared__ float s_w[T_DIM];
  __shared__ vf4 s_acc[32][8];
  __shared__ float s4[4];

  // ---- softmax over b's 1024 energies (redundant per block) ----
  const float4 ev = ((const float4*)(ws + WS_EN + (size_t)b * T_DIM))[tid];
  float m = fmaxf(fmaxf(ev.x, ev.y), fmaxf(ev.z, ev.w));
#pragma unroll
  for (int off = 32; off > 0; off >>= 1) m = fmaxf(m, __shfl_xor(m, off));
  if (lane == 0) s4[wave] = m;
  __syncthreads();
  const float M = fmaxf(fmaxf(s4[0], s4[1]), fmaxf(s4[2], s4[3]));
  __syncthreads();
  float4 ex;
  ex.x = __expf(ev.x - M);
  ex.y = __expf(ev.y - M);
  ex.z = __expf(ev.z - M);
  ex.w = __expf(ev.w - M);
  float s = ex.x + ex.y + ex.z + ex.w;
#pragma unroll
  for (int off = 32; off > 0; off >>= 1) s += __shfl_xor(s, off);
  if (lane == 0) s4[wave] = s;
  __syncthreads();
  const float inv = 1.f / (s4[0] + s4[1] + s4[2] + s4[3]);
  float4 wv;
  wv.x = ex.x * inv; wv.y = ex.y * inv; wv.z = ex.z * inv; wv.w = ex.w * inv;
  ((float4*)s_w)[tid] = wv;
  if (ec == 0) ((float4*)(out + B_DIM * E_DIM + (size_t)b * T_DIM))[tid] = wv;
  __syncthreads();

  // ---- context: acc[col] = sum_t w[t]*enc[b][t][col], cols = ec*32+[0,32) ----
  const int c = tid & 7;    // float4 col within chunk
  const int r = tid >> 3;   // 0..31, t stride 32
  const vf4* ep = (const vf4*)(enc + (size_t)b * T_DIM * E_DIM) + ec * 8 + c;
  vf4 acc = 0.f;
#pragma unroll 8
  for (int t = r; t < T_DIM; t += 32) {
    const vf4 v = __builtin_nontemporal_load(ep + (size_t)t * (E_DIM / 4));
    const float w = s_w[t];
    acc += w * v;
  }
  s_acc[r][c] = acc;
  __syncthreads();
  if (tid < 64) {
    const int cc = tid & 7;
    const int i = tid >> 3;  // 0..7
    vf4 sv = s_acc[i][cc];
#pragma unroll
    for (int j = 8; j < 32; j += 8) sv += s_acc[i + j][cc];
    s_acc[i][cc] = sv;
  }
  __syncthreads();
  if (tid < 8) {
    vf4 sv = s_acc[0][tid];
#pragma unroll
    for (int i = 1; i < 8; ++i) sv += s_acc[i][tid];
    ((vf4*)(out + (size_t)b * E_DIM))[ec * 8 + tid] = sv;
  }
}

// ---------------------------------------------------------------------------
extern "C" void kernel_launch(void* const* d_in, const int* in_sizes, int n_in,
                              void* d_out, int out_size, void* d_ws, size_t ws_size,
                              hipStream_t stream) {
  const float* enc    = (const float*)d_in[0];   // [64,1024,512]
  const float* peo    = (const float*)d_in[1];   // [64,1024,128]
  const float* lstm   = (const float*)d_in[2];   // [64,1,1024]
  const float* awc    = (const float*)d_in[3];   // [64,1024]
  const float* W_lstm = (const float*)d_in[4];   // [128,1024]
  const float* conv_w = (const float*)d_in[5];   // [32,1,31]
  const float* conv_b = (const float*)d_in[6];   // [32]
  const float* W_loc  = (const float*)d_in[7];   // [128,32]
  const float* b_loc  = (const float*)d_in[8];   // [128]
  const float* W_e    = (const float*)d_in[9];   // [1,128]
  const float* b_e    = (const float*)d_in[10];  // [1]
  float* out = (float*)d_out;
  float* ws  = (float*)d_ws;

  prep_kernel<<<4 * B_DIM + 1, 256, 0, stream>>>(lstm, W_lstm, conv_w, conv_b,
                                                 W_loc, b_loc, ws);
  energy_kernel<<<dim3(T_DIM / TCHUNK, B_DIM), 256, 0, stream>>>(peo, awc, W_e,
                                                                 b_e, ws);
  context_kernel<<<dim3(16, B_DIM), 256, 0, stream>>>(enc, ws, out);
}

// Round 11
// 54.258 us; speedup vs baseline: 1.0676x; 1.0676x over previous
//
#include <hip/hip_runtime.h>
#include <math.h>

#define B_DIM   64
#define T_DIM   1024
#define E_DIM   512
#define DL_DIM  1024
#define DA_DIM  128
#define CL_DIM  32
#define KW      31
#define KWP     32   // padded conv width (k=31 is zero)

// ws layout (float offsets)
#define WS_WCOMB 0            // 128*32 = 4096 (stride-32 padded rows)
#define WS_BCOMB 4096         // 128
#define WS_PL    4224         // 64*128 = 8192
#define WS_EN    16384        // 64*1024 = 65536
// total 81920 floats = 328 KB

// ---------------------------------------------------------------------------
// K1: blocks 0..255: processed_lstm. Block (b,q): rows a in [q*32, q*32+32).
//     8 threads per row, each a 128-elem sub-dot, 3-step shfl reduce.
//     block 256: Wcomb (stride-32, k=31 zeroed) and bcomb.
// ---------------------------------------------------------------------------
__global__ __launch_bounds__(256) void prep_kernel(
    const float* __restrict__ lstm,    // [B,1,DL]
    const float* __restrict__ W_lstm,  // [DA,DL]
    const float* __restrict__ conv_w,  // [CL,1,KW]
    const float* __restrict__ conv_b,  // [CL]
    const float* __restrict__ W_loc,   // [DA,CL]
    const float* __restrict__ b_loc,   // [DA]
    float* __restrict__ ws) {
  const int blk = blockIdx.x;
  const int tid = threadIdx.x;
  if (blk < 4 * B_DIM) {
    const int b = blk >> 2;
    const int q = blk & 3;
    const int a = q * 32 + (tid >> 3);  // 32 rows per block
    const int h = tid & 7;              // 8 sub-dots per row
    const float4* lv = (const float4*)(lstm + (size_t)b * DL_DIM + h * 128);
    const float4* wv = (const float4*)(W_lstm + (size_t)a * DL_DIM + h * 128);
    float acc = 0.f;
#pragma unroll 8
    for (int i = 0; i < 32; ++i) {
      const float4 x = lv[i], y = wv[i];
      acc = fmaf(x.x, y.x, acc);
      acc = fmaf(x.y, y.y, acc);
      acc = fmaf(x.z, y.z, acc);
      acc = fmaf(x.w, y.w, acc);
    }
    acc += __shfl_xor(acc, 1);
    acc += __shfl_xor(acc, 2);
    acc += __shfl_xor(acc, 4);
    if (h == 0) ws[WS_PL + b * DA_DIM + a] = acc;
  } else if (tid < DA_DIM) {
    const int a = tid;
    float wl[CL_DIM];
#pragma unroll
    for (int c = 0; c < CL_DIM; ++c) wl[c] = W_loc[a * CL_DIM + c];
    float bc = b_loc[a];
#pragma unroll
    for (int c = 0; c < CL_DIM; ++c) bc = fmaf(wl[c], conv_b[c], bc);
    ws[WS_BCOMB + a] = bc;
    for (int k = 0; k < KWP; ++k) {
      float s = 0.f;
      if (k < KW) {
#pragma unroll
        for (int c = 0; c < CL_DIM; ++c) s = fmaf(wl[c], conv_w[c * KW + k], s);
      }
      ws[WS_WCOMB + a * KWP + k] = s;
    }
  }
}

// ---------------------------------------------------------------------------
// K2: energies[b][t] = b_e + sum_a W_e[a] * tanh( pl[b][a] + bcomb[a]
//        + sum_k Wcomb[a][k]*awc_pad[b][t+k-15] + peo[b][t][a] )
// grid (16,64), block 256 = 4 waves; wave w owns t in [t0+16w, t0+16w+16).
// All FMA operands register-resident; one LDS transpose reduce at the end.
// ---------------------------------------------------------------------------
#define TCHUNK 64
__global__ __launch_bounds__(256, 2) void energy_kernel(
    const float* __restrict__ peo,  // [B,T,DA]
    const float* __restrict__ awc,  // [B,T]
    const float* __restrict__ W_e,  // [DA]
    const float* __restrict__ b_e,  // [1]
    float* __restrict__ ws) {
  const int b = blockIdx.y;
  const int t0 = blockIdx.x * TCHUNK;
  const int tid = threadIdx.x;
  const int lane = tid & 63;
  const int wave = tid >> 6;

  __shared__ float s_awc[96];          // window [t0-15, t0+80], pad zeros
  __shared__ float s_red[4][16][68];   // per-wave transpose buffer (pad 68)

  for (int i = tid; i < 96; i += 256) {
    const int g = t0 - (KW / 2) + i;
    s_awc[i] = (i < TCHUNK + KW - 1 && g >= 0 && g < T_DIM) ? awc[b * T_DIM + g] : 0.f;
  }
  __syncthreads();

  // ---- register copies: awc window (48) and Wcomb rows (2x32) ----
  float aw[48];
  {
    const float4* awp = (const float4*)(s_awc + wave * 16);
#pragma unroll
    for (int j = 0; j < 12; ++j) {
      const float4 q = awp[j];
      aw[4 * j + 0] = q.x; aw[4 * j + 1] = q.y;
      aw[4 * j + 2] = q.z; aw[4 * j + 3] = q.w;
    }
  }
  const int a0 = 2 * lane, a1 = 2 * lane + 1;
  float wc0[KWP], wc1[KWP];
  {
    const float4* w0p = (const float4*)(ws + WS_WCOMB + a0 * KWP);
    const float4* w1p = (const float4*)(ws + WS_WCOMB + a1 * KWP);
#pragma unroll
    for (int j = 0; j < 8; ++j) {
      const float4 q0 = w0p[j], q1 = w1p[j];
      wc0[4 * j + 0] = q0.x; wc0[4 * j + 1] = q0.y;
      wc0[4 * j + 2] = q0.z; wc0[4 * j + 3] = q0.w;
      wc1[4 * j + 0] = q1.x; wc1[4 * j + 1] = q1.y;
      wc1[4 * j + 2] = q1.z; wc1[4 * j + 3] = q1.w;
    }
  }
  const float base0 = ws[WS_PL + b * DA_DIM + a0] + ws[WS_BCOMB + a0];
  const float base1 = ws[WS_PL + b * DA_DIM + a1] + ws[WS_BCOMB + a1];
  const float we0 = W_e[a0], we1 = W_e[a1];
  const float be = b_e[0];

  // ---- main loop: 16 t's, all operands in registers ----
  float v[16];
#pragma unroll
  for (int i = 0; i < 16; ++i) {
    const int t = t0 + wave * 16 + i;
    const float2 p = *(const float2*)(peo + ((size_t)b * T_DIM + t) * DA_DIM + a0);
    float s0 = base0, s1 = base1;
#pragma unroll
    for (int k = 0; k < KWP; ++k) {
      s0 = fmaf(aw[i + k], wc0[k], s0);
      s1 = fmaf(aw[i + k], wc1[k], s1);
    }
    const float x0 = s0 + p.x;
    const float x1 = s1 + p.y;
    // overflow-safe tanh: sign(x)*(1-e)*rcp(1+e), e = exp(-2|x|)
    const float e0 = __expf(-2.f * fabsf(x0));
    const float e1 = __expf(-2.f * fabsf(x1));
    const float th0 = __builtin_copysignf((1.f - e0) * __builtin_amdgcn_rcpf(1.f + e0), x0);
    const float th1 = __builtin_copysignf((1.f - e1) * __builtin_amdgcn_rcpf(1.f + e1), x1);
    v[i] = fmaf(th0, we0, th1 * we1);
  }

  // ---- transpose reduce: 64 partials per t -> 1 energy, 16 t's at once ----
#pragma unroll
  for (int i = 0; i < 16; ++i) s_red[wave][i][lane] = v[i];
  __syncthreads();
  {
    const int t = lane >> 2;   // 0..15
    const int sub = lane & 3;  // 0..3
    const float4* rp = (const float4*)(&s_red[wave][t][sub * 16]);
    float4 q0 = rp[0], q1 = rp[1], q2 = rp[2], q3 = rp[3];
    float s = ((q0.x + q0.y) + (q0.z + q0.w)) + ((q1.x + q1.y) + (q1.z + q1.w))
            + ((q2.x + q2.y) + (q2.z + q2.w)) + ((q3.x + q3.y) + (q3.z + q3.w));
    s += __shfl_xor(s, 1);
    s += __shfl_xor(s, 2);
    if (sub == 0)
      ws[WS_EN + b * T_DIM + t0 + wave * 16 + t] = s + be;
  }
}

// ---------------------------------------------------------------------------
// K3: fused softmax (redundant per block; energies L2-resident) + context
// over a 32-column chunk x ALL 1024 t -> writes out DIRECTLY. grid (16,64),
// block 256. Disjoint columns per block -> no cross-block communication.
// Plain (cached) loads — nt variant measured slower (R10: L3 reuse is real).
// ---------------------------------------------------------------------------
__global__ __launch_bounds__(256) void context_kernel(
    const float* __restrict__ enc,  // [B,T,E]
    const float* __restrict__ ws,
    float* __restrict__ out) {      // [B*E context][B*T weights]
  const int b = blockIdx.y;
  const int ec = blockIdx.x;  // 0..15 (columns ec*32 .. ec*32+32)
  const int tid = threadIdx.x;
  const int lane = tid & 63;
  const int wave = tid >> 6;

  __shared__ float s_w[T_DIM];
  __shared__ float4 s_acc[32][8];
  __shared__ float s4[4];

  // ---- softmax over b's 1024 energies (redundant per block) ----
  const float4 ev = ((const float4*)(ws + WS_EN + (size_t)b * T_DIM))[tid];
  float m = fmaxf(fmaxf(ev.x, ev.y), fmaxf(ev.z, ev.w));
#pragma unroll
  for (int off = 32; off > 0; off >>= 1) m = fmaxf(m, __shfl_xor(m, off));
  if (lane == 0) s4[wave] = m;
  __syncthreads();
  const float M = fmaxf(fmaxf(s4[0], s4[1]), fmaxf(s4[2], s4[3]));
  __syncthreads();
  float4 ex;
  ex.x = __expf(ev.x - M);
  ex.y = __expf(ev.y - M);
  ex.z = __expf(ev.z - M);
  ex.w = __expf(ev.w - M);
  float s = ex.x + ex.y + ex.z + ex.w;
#pragma unroll
  for (int off = 32; off > 0; off >>= 1) s += __shfl_xor(s, off);
  if (lane == 0) s4[wave] = s;
  __syncthreads();
  const float inv = 1.f / (s4[0] + s4[1] + s4[2] + s4[3]);
  float4 wv;
  wv.x = ex.x * inv; wv.y = ex.y * inv; wv.z = ex.z * inv; wv.w = ex.w * inv;
  ((float4*)s_w)[tid] = wv;
  if (ec == 0) ((float4*)(out + B_DIM * E_DIM + (size_t)b * T_DIM))[tid] = wv;
  __syncthreads();

  // ---- context: acc[col] = sum_t w[t]*enc[b][t][col], cols = ec*32+[0,32) ----
  const int c = tid & 7;    // float4 col within chunk
  const int r = tid >> 3;   // 0..31, t stride 32
  const float4* ep = (const float4*)(enc + (size_t)b * T_DIM * E_DIM) + ec * 8 + c;
  float4 acc = make_float4(0.f, 0.f, 0.f, 0.f);
#pragma unroll 8
  for (int t = r; t < T_DIM; t += 32) {
    const float4 v = ep[(size_t)t * (E_DIM / 4)];
    const float w = s_w[t];
    acc.x = fmaf(w, v.x, acc.x);
    acc.y = fmaf(w, v.y, acc.y);
    acc.z = fmaf(w, v.z, acc.z);
    acc.w = fmaf(w, v.w, acc.w);
  }
  s_acc[r][c] = acc;
  __syncthreads();
  if (tid < 64) {
    const int cc = tid & 7;
    const int i = tid >> 3;  // 0..7
    float4 sv = s_acc[i][cc];
#pragma unroll
    for (int j = 8; j < 32; j += 8) {
      const float4 q = s_acc[i + j][cc];
      sv.x += q.x; sv.y += q.y; sv.z += q.z; sv.w += q.w;
    }
    s_acc[i][cc] = sv;
  }
  __syncthreads();
  if (tid < 8) {
    float4 sv = s_acc[0][tid];
#pragma unroll
    for (int i = 1; i < 8; ++i) {
      const float4 q = s_acc[i][tid];
      sv.x += q.x; sv.y += q.y; sv.z += q.z; sv.w += q.w;
    }
    ((float4*)(out + (size_t)b * E_DIM))[ec * 8 + tid] = sv;
  }
}

// ---------------------------------------------------------------------------
extern "C" void kernel_launch(void* const* d_in, const int* in_sizes, int n_in,
                              void* d_out, int out_size, void* d_ws, size_t ws_size,
                              hipStream_t stream) {
  const float* enc    = (const float*)d_in[0];   // [64,1024,512]
  const float* peo    = (const float*)d_in[1];   // [64,1024,128]
  const float* lstm   = (const float*)d_in[2];   // [64,1,1024]
  const float* awc    = (const float*)d_in[3];   // [64,1024]
  const float* W_lstm = (const float*)d_in[4];   // [128,1024]
  const float* conv_w = (const float*)d_in[5];   // [32,1,31]
  const float* conv_b = (const float*)d_in[6];   // [32]
  const float* W_loc  = (const float*)d_in[7];   // [128,32]
  const float* b_loc  = (const float*)d_in[8];   // [128]
  const float* W_e    = (const float*)d_in[9];   // [1,128]
  const float* b_e    = (const float*)d_in[10];  // [1]
  float* out = (float*)d_out;
  float* ws  = (float*)d_ws;

  prep_kernel<<<4 * B_DIM + 1, 256, 0, stream>>>(lstm, W_lstm, conv_w, conv_b,
                                                 W_loc, b_loc, ws);
  energy_kernel<<<dim3(T_DIM / TCHUNK, B_DIM), 256, 0, stream>>>(peo, awc, W_e,
                                                                 b_e, ws);
  context_kernel<<<dim3(16, B_DIM), 256, 0, stream>>>(enc, ws, out);
}